// Round 11
// baseline (226.239 us; speedup 1.0000x reference)
//
#include <hip/hip_runtime.h>
#include <hip/hip_bf16.h>
#include <math.h>

// Problem constants (fixed by setup_inputs: B=8, M=1024, D=256, H=W=100)
#define BATCH 8
#define MQ    1024
#define DIM   256
#define NHEAD 8
#define NPTS  4
#define NPROJ 98            // 64 offsets + 32 attn logits + 2 base-ref
#define PSTR  112           // padded projection row stride (floats)

typedef __attribute__((ext_vector_type(8))) short  short8;  // 8 bf16 = 4 VGPR
typedef __attribute__((ext_vector_type(4))) float  f32x4;

static __device__ __forceinline__ ushort f2bf(float f) {
    union { float f; unsigned u; } v; v.f = f;
    const unsigned r = v.u + 0x7fffu + ((v.u >> 16) & 1u);   // round-nearest-even
    return (ushort)(r >> 16);
}

// Per-scalar liveness hammer (float4 "+v" is a tied indirect constraint ->
// unsupported on gfx950; scalar floats are single VGPRs and compile fine).
#define KEEP4(v) asm volatile("" : "+v"(v.x), "+v"(v.y), "+v"(v.z), "+v"(v.w))

// ---------------------------------------------------------------------------
// Build Wcat[256][112] = [Wo | Wa | Wr | 0-pad] and bcat[112] (once, ~1 us).
// ---------------------------------------------------------------------------
__global__ __launch_bounds__(112) void wcat_build_kernel(
    const float* __restrict__ Wo, const float* __restrict__ bo,
    const float* __restrict__ Wa, const float* __restrict__ ba,
    const float* __restrict__ Wr, const float* __restrict__ br,
    float* __restrict__ Wcat, float* __restrict__ bcat)
{
    const int k = blockIdx.x;      // 0..255
    const int j = threadIdx.x;     // 0..111
    float w = 0.f, bias = 0.f;
    if (j < 64)      { w = Wo[k * 64 + j];        bias = bo[j]; }
    else if (j < 96) { w = Wa[k * 32 + (j - 64)]; bias = ba[j - 64]; }
    else if (j < 98) { w = Wr[k * 2  + (j - 96)]; bias = br[j - 96]; }
    Wcat[k * PSTR + j] = w;
    if (k == 0) bcat[j] = bias;
}

// ---------------------------------------------------------------------------
// Projection GEMM (fp32): P[8192][112] = SADQ @ Wcat + bcat.
// v2: 512 blocks x 256 threads; block = 16 rows; thread = 1 row x 7 cols;
// KC=32 k-chunks. LDS 16KB -> 2 blocks/CU, 8 waves/CU (v1 was 1 block = 4
// waves/CU, latency-bound). Bank check: Ws stride 7 coprime 32 -> conflict-
// free; Qs row-broadcast with 2-way alias (free, m136).
// fp32 is required: bf16 offsets shift sample positions ~0.15px -> fails.
// ---------------------------------------------------------------------------
__global__ __launch_bounds__(256) void proj_kernel(
    const float* __restrict__ SADQ,   // [BM, 256]
    const float* __restrict__ Wcat,   // [256, 112]
    const float* __restrict__ bcat,   // [112]
    float* __restrict__ P)            // [BM, 112]
{
    __shared__ float Qs[16][36];      // 16 rows x 32 k (pad 36: fl4-aligned)
    __shared__ float Ws[32][112];

    const int tid  = threadIdx.x;
    const int row0 = blockIdx.x * 16;
    const int rg   = tid >> 4;        // 0..15: row
    const int cg   = tid & 15;        // 0..15: 7-col group

    float acc[7] = {};

    for (int kc = 0; kc < DIM; kc += 32) {
        if (tid < 128) {              // 16 rows x 8 float4 = 128
            const int r  = tid >> 3;
            const int k4 = (tid & 7) * 4;
            const float4 v = *(const float4*)&SADQ[(size_t)(row0 + r) * DIM + kc + k4];
            Qs[r][k4 + 0] = v.x; Qs[r][k4 + 1] = v.y;
            Qs[r][k4 + 2] = v.z; Qs[r][k4 + 3] = v.w;
        }
        for (int fi = tid; fi < 32 * 28; fi += 256) {   // 28 float4 per k-row
            const int k  = fi / 28;
            const int j4 = (fi % 28) * 4;
            *(float4*)&Ws[k][j4] = *(const float4*)&Wcat[(size_t)(kc + k) * PSTR + j4];
        }
        __syncthreads();

        #pragma unroll 8
        for (int k = 0; k < 32; ++k) {
            const float q = Qs[rg][k];
            #pragma unroll
            for (int j = 0; j < 7; ++j)
                acc[j] = fmaf(q, Ws[k][cg * 7 + j], acc[j]);
        }
        __syncthreads();
    }

    #pragma unroll
    for (int j = 0; j < 7; ++j) {
        const int col = cg * 7 + j;
        P[(size_t)(row0 + rg) * PSTR + col] = acc[j] + bcat[col];
    }
}

// ---------------------------------------------------------------------------
// Gather kernel: one WAVE per row (4 rows/block). NEW: batch->XCD swizzle.
// 8 batches map 1:1 onto 8 XCDs (round-robin dispatch, m09): XCD x only
// touches batch x's 10MB E-slice -> L2 working set /8 (was 80MB thrash,
// FETCH 194MB = 2.4x over-fetch of E).
// ---------------------------------------------------------------------------
__global__ __launch_bounds__(256) void gather_kernel(
    const float* __restrict__ P,      // [BM, 112]
    const float* __restrict__ E,      // [B, H*W, 256]
    const int*   __restrict__ Hp, const int* __restrict__ Wdp,
    ushort* __restrict__ aggb)        // [BM, 256] bf16
{
    const int tid  = threadIdx.x;
    const int wid  = tid >> 6;        // wave in block 0..3
    const int lane = tid & 63;
    // XCD swizzle: bijective for gridDim.x % 8 == 0 (2048 here).
    const int bid  = blockIdx.x;
    const int cpx  = (int)(gridDim.x >> 3);
    const int sb   = (bid & 7) * cpx + (bid >> 3);
    const int row  = sb * 4 + wid;
    const int b    = row >> 10;       // MQ = 1024

    __shared__ float sW[4][128];
    __shared__ int   sIdx[4][128];    // pixel index in float4 units

    const int Hh = *Hp;
    const int Ww = *Wdp;

    if (lane < 32) {
        const int p = lane;           // point h*4+pt
        const float* Pr = P + (size_t)row * PSTR;
        const float lg = Pr[64 + p];
        float mx = fmaxf(lg, __shfl_xor(lg, 1));
        mx = fmaxf(mx, __shfl_xor(mx, 2));
        const float e = expf(lg - mx);
        float s = e + __shfl_xor(e, 1);
        s += __shfl_xor(s, 2);
        const float aw = e / s * (1.f / NHEAD);

        const float lx = Pr[96] + 0.1f * Pr[p * 2 + 0];
        const float ly = Pr[97] + 0.1f * Pr[p * 2 + 1];
        const float ix = ((lx + 1.f) * (float)Ww - 1.f) * 0.5f;
        const float iy = ((ly + 1.f) * (float)Hh - 1.f) * 0.5f;
        const float x0f = floorf(ix), y0f = floorf(iy);
        const int   x0  = (int)x0f,   y0  = (int)y0f;
        const float wx1 = ix - x0f, wx0 = 1.f - wx1;
        const float wy1 = iy - y0f, wy0 = 1.f - wy1;

        #pragma unroll
        for (int c = 0; c < 4; ++c) {
            const int   xc = x0 + (c & 1);
            const int   yc = y0 + (c >> 1);
            const float wx = (c & 1) ? wx1 : wx0;
            const float wy = (c >> 1) ? wy1 : wy0;
            const bool valid = (xc >= 0) && (xc < Ww) && (yc >= 0) && (yc < Hh);
            const int xi = min(max(xc, 0), Ww - 1);
            const int yi = min(max(yc, 0), Hh - 1);
            sW  [wid][p * 4 + c] = valid ? (wx * wy * aw) : 0.f;
            sIdx[wid][p * 4 + c] = (yi * Ww + xi) * (DIM / 4);
        }
    }
    __syncthreads();

    const float4* __restrict__ Eb4 =
        (const float4*)(E + (size_t)b * (size_t)(Hh * Ww) * DIM);

    float4 acc = make_float4(0.f, 0.f, 0.f, 0.f);
    for (int t = 0; t < 128; t += 8) {
        const float w0 = sW[wid][t + 0]; const int i0 = sIdx[wid][t + 0];
        const float w1 = sW[wid][t + 1]; const int i1 = sIdx[wid][t + 1];
        const float w2 = sW[wid][t + 2]; const int i2 = sIdx[wid][t + 2];
        const float w3 = sW[wid][t + 3]; const int i3 = sIdx[wid][t + 3];
        const float w4 = sW[wid][t + 4]; const int i4 = sIdx[wid][t + 4];
        const float w5 = sW[wid][t + 5]; const int i5 = sIdx[wid][t + 5];
        const float w6 = sW[wid][t + 6]; const int i6 = sIdx[wid][t + 6];
        const float w7 = sW[wid][t + 7]; const int i7 = sIdx[wid][t + 7];

        float4 e0 = Eb4[(size_t)i0 + lane];
        float4 e1 = Eb4[(size_t)i1 + lane];
        float4 e2 = Eb4[(size_t)i2 + lane];
        float4 e3 = Eb4[(size_t)i3 + lane];
        float4 e4 = Eb4[(size_t)i4 + lane];
        float4 e5 = Eb4[(size_t)i5 + lane];
        float4 e6 = Eb4[(size_t)i6 + lane];
        float4 e7 = Eb4[(size_t)i7 + lane];
        // Liveness hammer (per-scalar): force all 8 loads in flight before
        // any FMA consumes them (R5/R6: compiler re-serializes otherwise).
        KEEP4(e0); KEEP4(e1); KEEP4(e2); KEEP4(e3);
        KEEP4(e4); KEEP4(e5); KEEP4(e6); KEEP4(e7);

        acc.x = fmaf(w0, e0.x, acc.x); acc.y = fmaf(w0, e0.y, acc.y);
        acc.z = fmaf(w0, e0.z, acc.z); acc.w = fmaf(w0, e0.w, acc.w);
        acc.x = fmaf(w1, e1.x, acc.x); acc.y = fmaf(w1, e1.y, acc.y);
        acc.z = fmaf(w1, e1.z, acc.z); acc.w = fmaf(w1, e1.w, acc.w);
        acc.x = fmaf(w2, e2.x, acc.x); acc.y = fmaf(w2, e2.y, acc.y);
        acc.z = fmaf(w2, e2.z, acc.z); acc.w = fmaf(w2, e2.w, acc.w);
        acc.x = fmaf(w3, e3.x, acc.x); acc.y = fmaf(w3, e3.y, acc.y);
        acc.z = fmaf(w3, e3.z, acc.z); acc.w = fmaf(w3, e3.w, acc.w);
        acc.x = fmaf(w4, e4.x, acc.x); acc.y = fmaf(w4, e4.y, acc.y);
        acc.z = fmaf(w4, e4.z, acc.z); acc.w = fmaf(w4, e4.w, acc.w);
        acc.x = fmaf(w5, e5.x, acc.x); acc.y = fmaf(w5, e5.y, acc.y);
        acc.z = fmaf(w5, e5.z, acc.z); acc.w = fmaf(w5, e5.w, acc.w);
        acc.x = fmaf(w6, e6.x, acc.x); acc.y = fmaf(w6, e6.y, acc.y);
        acc.z = fmaf(w6, e6.z, acc.z); acc.w = fmaf(w6, e6.w, acc.w);
        acc.x = fmaf(w7, e7.x, acc.x); acc.y = fmaf(w7, e7.y, acc.y);
        acc.z = fmaf(w7, e7.z, acc.z); acc.w = fmaf(w7, e7.w, acc.w);
    }

    ushort4 o;
    o.x = f2bf(acc.x); o.y = f2bf(acc.y);
    o.z = f2bf(acc.z); o.w = f2bf(acc.w);
    *(ushort4*)&aggb[(size_t)row * DIM + lane * 4] = o;
}

// ---------------------------------------------------------------------------
// Tiny kernel: WpT[n][k] = bf16(Wp[k][n]).  (unchanged)
// ---------------------------------------------------------------------------
__global__ __launch_bounds__(256) void wp_convert_kernel(
    const float* __restrict__ Wp, ushort* __restrict__ WpT)
{
    const int k = blockIdx.x;
    const int n = threadIdx.x;
    WpT[(size_t)n * DIM + k] = f2bf(Wp[(size_t)k * DIM + n]);
}

// ---------------------------------------------------------------------------
// Kernel B: out = agg @ Wp + bp via bf16 MFMA (fp32 accumulate). (unchanged)
// ---------------------------------------------------------------------------
__global__ __launch_bounds__(256) void mfma_gemm_kernel(
    const ushort* __restrict__ A,     // [M, 256] bf16
    const ushort* __restrict__ BT,    // [256, 256] bf16 (transposed Wp)
    const float*  __restrict__ bp,    // [256]
    float* __restrict__ out)          // [M, 256]
{
    __shared__ ushort ldsA[64 * 40];
    __shared__ ushort ldsB[64 * 40];

    const int tid  = threadIdx.x;
    const int mb   = blockIdx.x * 64;
    const int nb   = blockIdx.y * 64;
    const int wave = tid >> 6;
    const int lane = tid & 63;
    const int r0   = (wave >> 1) * 32;
    const int c0   = (wave & 1) * 32;
    const int lrow = lane & 15;
    const int kgrp = lane >> 4;

    const int sm = tid >> 2;
    const int sc = (tid & 3) * 8;

    f32x4 acc00 = {0.f, 0.f, 0.f, 0.f};
    f32x4 acc01 = {0.f, 0.f, 0.f, 0.f};
    f32x4 acc10 = {0.f, 0.f, 0.f, 0.f};
    f32x4 acc11 = {0.f, 0.f, 0.f, 0.f};

    for (int kb = 0; kb < DIM; kb += 32) {
        *(uint4*)&ldsA[sm * 40 + sc] =
            *(const uint4*)&A[(size_t)(mb + sm) * DIM + kb + sc];
        *(uint4*)&ldsB[sm * 40 + sc] =
            *(const uint4*)&BT[(size_t)(nb + sm) * DIM + kb + sc];
        __syncthreads();

        const short8 a0 = *(const short8*)&ldsA[(r0 + lrow)      * 40 + kgrp * 8];
        const short8 a1 = *(const short8*)&ldsA[(r0 + 16 + lrow) * 40 + kgrp * 8];
        const short8 b0 = *(const short8*)&ldsB[(c0 + lrow)      * 40 + kgrp * 8];
        const short8 b1 = *(const short8*)&ldsB[(c0 + 16 + lrow) * 40 + kgrp * 8];

        acc00 = __builtin_amdgcn_mfma_f32_16x16x32_bf16(a0, b0, acc00, 0, 0, 0);
        acc01 = __builtin_amdgcn_mfma_f32_16x16x32_bf16(a0, b1, acc01, 0, 0, 0);
        acc10 = __builtin_amdgcn_mfma_f32_16x16x32_bf16(a1, b0, acc10, 0, 0, 0);
        acc11 = __builtin_amdgcn_mfma_f32_16x16x32_bf16(a1, b1, acc11, 0, 0, 0);
        __syncthreads();
    }

    const int orow = mb + r0 + kgrp * 4;
    const int ocol = nb + c0 + lrow;
    const float bp0 = bp[ocol];
    const float bp1 = bp[ocol + 16];
    #pragma unroll
    for (int reg = 0; reg < 4; ++reg) {
        out[(size_t)(orow + reg)      * DIM + ocol]      = acc00[reg] + bp0;
        out[(size_t)(orow + reg)      * DIM + ocol + 16] = acc01[reg] + bp1;
        out[(size_t)(orow + 16 + reg) * DIM + ocol]      = acc10[reg] + bp0;
        out[(size_t)(orow + 16 + reg) * DIM + ocol + 16] = acc11[reg] + bp1;
    }
}

// ---------------------------------------------------------------------------
extern "C" void kernel_launch(void* const* d_in, const int* in_sizes, int n_in,
                              void* d_out, int out_size, void* d_ws, size_t ws_size,
                              hipStream_t stream)
{
    const float* SADQ = (const float*)d_in[0];
    const float* E    = (const float*)d_in[1];
    const float* Wo   = (const float*)d_in[2];
    const float* bo   = (const float*)d_in[3];
    const float* Wa   = (const float*)d_in[4];
    const float* ba   = (const float*)d_in[5];
    const float* Wr   = (const float*)d_in[6];
    const float* br   = (const float*)d_in[7];
    const float* Wp   = (const float*)d_in[8];
    const float* bp   = (const float*)d_in[9];
    const int*   Hp   = (const int*)d_in[10];
    const int*   Wdp  = (const int*)d_in[11];

    const int BM = in_sizes[0] / DIM;          // 8192 rows

    // Workspace layout (bytes):
    //   aggb: [BM][256] bf16   = 4,194,304
    //   WpT : [256][256] bf16  =   131,072
    //   P   : [BM][112] fp32   = 3,670,016
    //   Wcat: [256][112] fp32  =   114,688
    //   bcat: [112] fp32       =       448
    char* ws = (char*)d_ws;
    ushort* aggb = (ushort*)(ws);
    ushort* WpT  = (ushort*)(ws + 4194304);
    float*  P    = (float*) (ws + 4194304 + 131072);
    float*  Wcat = (float*) (ws + 4194304 + 131072 + 3670016);
    float*  bcat = (float*) (ws + 4194304 + 131072 + 3670016 + 114688);
    float*  out  = (float*)d_out;

    wcat_build_kernel<<<DIM, PSTR, 0, stream>>>(Wo, bo, Wa, ba, Wr, br, Wcat, bcat);
    proj_kernel<<<BM / 16, 256, 0, stream>>>(SADQ, Wcat, bcat, P);
    gather_kernel<<<BM / 4, 256, 0, stream>>>(P, E, Hp, Wdp, aggb);
    wp_convert_kernel<<<DIM, 256, 0, stream>>>(Wp, WpT);

    dim3 g2(BM / 64, DIM / 64);
    mfma_gemm_kernel<<<g2, 256, 0, stream>>>(aggb, WpT, bp, out);
}

// Round 12
// 204.078 us; speedup vs baseline: 1.1086x; 1.1086x over previous
//
#include <hip/hip_runtime.h>
#include <hip/hip_bf16.h>
#include <math.h>

// Problem constants (fixed by setup_inputs: B=8, M=1024, D=256, H=W=100)
#define BATCH 8
#define MQ    1024
#define DIM   256
#define NHEAD 8
#define NPTS  4
#define NPROJ 98            // 64 offsets + 32 attn logits + 2 base-ref
#define PSTR  112           // projection row stride (floats)
#define NPAD  128           // padded N for the proj MFMA GEMM

typedef __attribute__((ext_vector_type(8))) short  short8;  // 8 bf16 = 4 VGPR
typedef __attribute__((ext_vector_type(4))) float  f32x4;

static __device__ __forceinline__ ushort f2bf(float f) {
    union { float f; unsigned u; } v; v.f = f;
    const unsigned r = v.u + 0x7fffu + ((v.u >> 16) & 1u);   // round-nearest-even
    return (ushort)(r >> 16);
}
static __device__ __forceinline__ float bf2f(ushort h) {
    union { unsigned u; float f; } v; v.u = ((unsigned)h) << 16;
    return v.f;
}

// Per-scalar liveness hammer (float4 "+v" is a tied indirect constraint ->
// unsupported on gfx950; scalars are single VGPRs and compile fine).
#define KEEP4(v) asm volatile("" : "+v"(v.x), "+v"(v.y), "+v"(v.z), "+v"(v.w))

// ---------------------------------------------------------------------------
// SADQ -> bf16 hi/lo split (a = hi + lo + O(2^-18 a)). 8MB read, 8MB write.
// ---------------------------------------------------------------------------
__global__ __launch_bounds__(256) void sadq_split_kernel(
    const float* __restrict__ SADQ, ushort* __restrict__ Ahi,
    ushort* __restrict__ Alo)
{
    const size_t i4 = (size_t)blockIdx.x * 256 + threadIdx.x;  // float4 index
    const float4 v = ((const float4*)SADQ)[i4];
    ushort4 hi, lo;
    hi.x = f2bf(v.x); lo.x = f2bf(v.x - bf2f(hi.x));
    hi.y = f2bf(v.y); lo.y = f2bf(v.y - bf2f(hi.y));
    hi.z = f2bf(v.z); lo.z = f2bf(v.z - bf2f(hi.z));
    hi.w = f2bf(v.w); lo.w = f2bf(v.w - bf2f(hi.w));
    ((ushort4*)Ahi)[i4] = hi;
    ((ushort4*)Alo)[i4] = lo;
}

// ---------------------------------------------------------------------------
// Build transposed concat weights, bf16 hi/lo: WcT*[n][k], n in [0,128) with
// rows [112,128) zero; bcat[n] biases. Tiny (one-time).
// ---------------------------------------------------------------------------
__global__ __launch_bounds__(128) void wsplit_build_kernel(
    const float* __restrict__ Wo, const float* __restrict__ bo,
    const float* __restrict__ Wa, const float* __restrict__ ba,
    const float* __restrict__ Wr, const float* __restrict__ br,
    ushort* __restrict__ WcTh, ushort* __restrict__ WcTl,
    float* __restrict__ bcat)
{
    const int k = blockIdx.x;      // 0..255
    const int n = threadIdx.x;     // 0..127
    float w = 0.f, bias = 0.f;
    if (n < 64)      { w = Wo[k * 64 + n];        bias = bo[n]; }
    else if (n < 96) { w = Wa[k * 32 + (n - 64)]; bias = ba[n - 64]; }
    else if (n < 98) { w = Wr[k * 2  + (n - 96)]; bias = br[n - 96]; }
    const ushort hi = f2bf(w);
    const ushort lo = f2bf(w - bf2f(hi));
    WcTh[(size_t)n * DIM + k] = hi;
    WcTl[(size_t)n * DIM + k] = lo;
    if (k == 0) bcat[n] = bias;
}

// ---------------------------------------------------------------------------
// Projection via MFMA with bf16 hi/lo 3-term split (fp32-grade accuracy):
// P[8192][112] = SADQ @ Wcat + bcat.  64x64 tile, 4 waves 2x2, BK=32.
// Identical (verified) fragment layout to mfma_gemm_kernel; 3 MFMAs per
// fragment pair: ahi*bhi + ahi*blo + alo*bhi (alo*blo ~ 2^-18, dropped).
// Replaces the scalar-LDS proj_kernel (LDS-throughput-bound, ~40us).
// ---------------------------------------------------------------------------
__global__ __launch_bounds__(256) void proj_mfma_kernel(
    const ushort* __restrict__ Ahi,   // [BM, 256] bf16
    const ushort* __restrict__ Alo,   // [BM, 256] bf16
    const ushort* __restrict__ BTh,   // [128, 256] bf16 (transposed Wcat hi)
    const ushort* __restrict__ BTl,   // [128, 256] bf16 (lo)
    const float*  __restrict__ bcat,  // [128]
    float* __restrict__ P)            // [BM, 112]
{
    __shared__ ushort ldsAh[64 * 40];
    __shared__ ushort ldsAl[64 * 40];
    __shared__ ushort ldsBh[64 * 40];
    __shared__ ushort ldsBl[64 * 40];

    const int tid  = threadIdx.x;
    const int mb   = blockIdx.x * 64;
    const int nb   = blockIdx.y * 64;
    const int wave = tid >> 6;
    const int lane = tid & 63;
    const int r0   = (wave >> 1) * 32;
    const int c0   = (wave & 1) * 32;
    const int lrow = lane & 15;
    const int kgrp = lane >> 4;

    const int sm = tid >> 2;
    const int sc = (tid & 3) * 8;

    f32x4 acc00 = {0.f, 0.f, 0.f, 0.f};
    f32x4 acc01 = {0.f, 0.f, 0.f, 0.f};
    f32x4 acc10 = {0.f, 0.f, 0.f, 0.f};
    f32x4 acc11 = {0.f, 0.f, 0.f, 0.f};

    for (int kb = 0; kb < DIM; kb += 32) {
        *(uint4*)&ldsAh[sm * 40 + sc] =
            *(const uint4*)&Ahi[(size_t)(mb + sm) * DIM + kb + sc];
        *(uint4*)&ldsAl[sm * 40 + sc] =
            *(const uint4*)&Alo[(size_t)(mb + sm) * DIM + kb + sc];
        *(uint4*)&ldsBh[sm * 40 + sc] =
            *(const uint4*)&BTh[(size_t)(nb + sm) * DIM + kb + sc];
        *(uint4*)&ldsBl[sm * 40 + sc] =
            *(const uint4*)&BTl[(size_t)(nb + sm) * DIM + kb + sc];
        __syncthreads();

        const short8 a0h = *(const short8*)&ldsAh[(r0 + lrow)      * 40 + kgrp * 8];
        const short8 a1h = *(const short8*)&ldsAh[(r0 + 16 + lrow) * 40 + kgrp * 8];
        const short8 a0l = *(const short8*)&ldsAl[(r0 + lrow)      * 40 + kgrp * 8];
        const short8 a1l = *(const short8*)&ldsAl[(r0 + 16 + lrow) * 40 + kgrp * 8];
        const short8 b0h = *(const short8*)&ldsBh[(c0 + lrow)      * 40 + kgrp * 8];
        const short8 b1h = *(const short8*)&ldsBh[(c0 + 16 + lrow) * 40 + kgrp * 8];
        const short8 b0l = *(const short8*)&ldsBl[(c0 + lrow)      * 40 + kgrp * 8];
        const short8 b1l = *(const short8*)&ldsBl[(c0 + 16 + lrow) * 40 + kgrp * 8];

        acc00 = __builtin_amdgcn_mfma_f32_16x16x32_bf16(a0h, b0h, acc00, 0, 0, 0);
        acc01 = __builtin_amdgcn_mfma_f32_16x16x32_bf16(a0h, b1h, acc01, 0, 0, 0);
        acc10 = __builtin_amdgcn_mfma_f32_16x16x32_bf16(a1h, b0h, acc10, 0, 0, 0);
        acc11 = __builtin_amdgcn_mfma_f32_16x16x32_bf16(a1h, b1h, acc11, 0, 0, 0);
        acc00 = __builtin_amdgcn_mfma_f32_16x16x32_bf16(a0h, b0l, acc00, 0, 0, 0);
        acc01 = __builtin_amdgcn_mfma_f32_16x16x32_bf16(a0h, b1l, acc01, 0, 0, 0);
        acc10 = __builtin_amdgcn_mfma_f32_16x16x32_bf16(a1h, b0l, acc10, 0, 0, 0);
        acc11 = __builtin_amdgcn_mfma_f32_16x16x32_bf16(a1h, b1l, acc11, 0, 0, 0);
        acc00 = __builtin_amdgcn_mfma_f32_16x16x32_bf16(a0l, b0h, acc00, 0, 0, 0);
        acc01 = __builtin_amdgcn_mfma_f32_16x16x32_bf16(a0l, b1h, acc01, 0, 0, 0);
        acc10 = __builtin_amdgcn_mfma_f32_16x16x32_bf16(a1l, b0h, acc10, 0, 0, 0);
        acc11 = __builtin_amdgcn_mfma_f32_16x16x32_bf16(a1l, b1h, acc11, 0, 0, 0);
        __syncthreads();
    }

    // Epilogue: D col=lane&15, row=(lane>>4)*4+reg. Guard n<112.
    const int orow  = mb + r0 + kgrp * 4;
    const int ocol0 = nb + c0 + lrow;
    const int ocol1 = ocol0 + 16;
    const float bc0 = bcat[ocol0];
    const float bc1 = bcat[ocol1];
    #pragma unroll
    for (int reg = 0; reg < 4; ++reg) {
        if (ocol0 < PSTR) {
            P[(size_t)(orow + reg)      * PSTR + ocol0] = acc00[reg] + bc0;
            P[(size_t)(orow + 16 + reg) * PSTR + ocol0] = acc10[reg] + bc0;
        }
        if (ocol1 < PSTR) {
            P[(size_t)(orow + reg)      * PSTR + ocol1] = acc01[reg] + bc1;
            P[(size_t)(orow + 16 + reg) * PSTR + ocol1] = acc11[reg] + bc1;
        }
    }
}

// ---------------------------------------------------------------------------
// Gather kernel: one WAVE per row (4 rows/block) + batch->XCD swizzle
// (verified R11: FETCH 194->113MB). (unchanged)
// ---------------------------------------------------------------------------
__global__ __launch_bounds__(256) void gather_kernel(
    const float* __restrict__ P,      // [BM, 112]
    const float* __restrict__ E,      // [B, H*W, 256]
    const int*   __restrict__ Hp, const int* __restrict__ Wdp,
    ushort* __restrict__ aggb)        // [BM, 256] bf16
{
    const int tid  = threadIdx.x;
    const int wid  = tid >> 6;        // wave in block 0..3
    const int lane = tid & 63;
    // XCD swizzle: bijective for gridDim.x % 8 == 0 (2048 here).
    const int bid  = blockIdx.x;
    const int cpx  = (int)(gridDim.x >> 3);
    const int sb   = (bid & 7) * cpx + (bid >> 3);
    const int row  = sb * 4 + wid;
    const int b    = row >> 10;       // MQ = 1024

    __shared__ float sW[4][128];
    __shared__ int   sIdx[4][128];    // pixel index in float4 units

    const int Hh = *Hp;
    const int Ww = *Wdp;

    if (lane < 32) {
        const int p = lane;           // point h*4+pt
        const float* Pr = P + (size_t)row * PSTR;
        const float lg = Pr[64 + p];
        float mx = fmaxf(lg, __shfl_xor(lg, 1));
        mx = fmaxf(mx, __shfl_xor(mx, 2));
        const float e = expf(lg - mx);
        float s = e + __shfl_xor(e, 1);
        s += __shfl_xor(s, 2);
        const float aw = e / s * (1.f / NHEAD);

        const float lx = Pr[96] + 0.1f * Pr[p * 2 + 0];
        const float ly = Pr[97] + 0.1f * Pr[p * 2 + 1];
        const float ix = ((lx + 1.f) * (float)Ww - 1.f) * 0.5f;
        const float iy = ((ly + 1.f) * (float)Hh - 1.f) * 0.5f;
        const float x0f = floorf(ix), y0f = floorf(iy);
        const int   x0  = (int)x0f,   y0  = (int)y0f;
        const float wx1 = ix - x0f, wx0 = 1.f - wx1;
        const float wy1 = iy - y0f, wy0 = 1.f - wy1;

        #pragma unroll
        for (int c = 0; c < 4; ++c) {
            const int   xc = x0 + (c & 1);
            const int   yc = y0 + (c >> 1);
            const float wx = (c & 1) ? wx1 : wx0;
            const float wy = (c >> 1) ? wy1 : wy0;
            const bool valid = (xc >= 0) && (xc < Ww) && (yc >= 0) && (yc < Hh);
            const int xi = min(max(xc, 0), Ww - 1);
            const int yi = min(max(yc, 0), Hh - 1);
            sW  [wid][p * 4 + c] = valid ? (wx * wy * aw) : 0.f;
            sIdx[wid][p * 4 + c] = (yi * Ww + xi) * (DIM / 4);
        }
    }
    __syncthreads();

    const float4* __restrict__ Eb4 =
        (const float4*)(E + (size_t)b * (size_t)(Hh * Ww) * DIM);

    float4 acc = make_float4(0.f, 0.f, 0.f, 0.f);
    for (int t = 0; t < 128; t += 8) {
        const float w0 = sW[wid][t + 0]; const int i0 = sIdx[wid][t + 0];
        const float w1 = sW[wid][t + 1]; const int i1 = sIdx[wid][t + 1];
        const float w2 = sW[wid][t + 2]; const int i2 = sIdx[wid][t + 2];
        const float w3 = sW[wid][t + 3]; const int i3 = sIdx[wid][t + 3];
        const float w4 = sW[wid][t + 4]; const int i4 = sIdx[wid][t + 4];
        const float w5 = sW[wid][t + 5]; const int i5 = sIdx[wid][t + 5];
        const float w6 = sW[wid][t + 6]; const int i6 = sIdx[wid][t + 6];
        const float w7 = sW[wid][t + 7]; const int i7 = sIdx[wid][t + 7];

        float4 e0 = Eb4[(size_t)i0 + lane];
        float4 e1 = Eb4[(size_t)i1 + lane];
        float4 e2 = Eb4[(size_t)i2 + lane];
        float4 e3 = Eb4[(size_t)i3 + lane];
        float4 e4 = Eb4[(size_t)i4 + lane];
        float4 e5 = Eb4[(size_t)i5 + lane];
        float4 e6 = Eb4[(size_t)i6 + lane];
        float4 e7 = Eb4[(size_t)i7 + lane];
        // Liveness hammer (per-scalar): force all 8 loads in flight before
        // any FMA consumes them (R5/R6: compiler re-serializes otherwise).
        KEEP4(e0); KEEP4(e1); KEEP4(e2); KEEP4(e3);
        KEEP4(e4); KEEP4(e5); KEEP4(e6); KEEP4(e7);

        acc.x = fmaf(w0, e0.x, acc.x); acc.y = fmaf(w0, e0.y, acc.y);
        acc.z = fmaf(w0, e0.z, acc.z); acc.w = fmaf(w0, e0.w, acc.w);
        acc.x = fmaf(w1, e1.x, acc.x); acc.y = fmaf(w1, e1.y, acc.y);
        acc.z = fmaf(w1, e1.z, acc.z); acc.w = fmaf(w1, e1.w, acc.w);
        acc.x = fmaf(w2, e2.x, acc.x); acc.y = fmaf(w2, e2.y, acc.y);
        acc.z = fmaf(w2, e2.z, acc.z); acc.w = fmaf(w2, e2.w, acc.w);
        acc.x = fmaf(w3, e3.x, acc.x); acc.y = fmaf(w3, e3.y, acc.y);
        acc.z = fmaf(w3, e3.z, acc.z); acc.w = fmaf(w3, e3.w, acc.w);
        acc.x = fmaf(w4, e4.x, acc.x); acc.y = fmaf(w4, e4.y, acc.y);
        acc.z = fmaf(w4, e4.z, acc.z); acc.w = fmaf(w4, e4.w, acc.w);
        acc.x = fmaf(w5, e5.x, acc.x); acc.y = fmaf(w5, e5.y, acc.y);
        acc.z = fmaf(w5, e5.z, acc.z); acc.w = fmaf(w5, e5.w, acc.w);
        acc.x = fmaf(w6, e6.x, acc.x); acc.y = fmaf(w6, e6.y, acc.y);
        acc.z = fmaf(w6, e6.z, acc.z); acc.w = fmaf(w6, e6.w, acc.w);
        acc.x = fmaf(w7, e7.x, acc.x); acc.y = fmaf(w7, e7.y, acc.y);
        acc.z = fmaf(w7, e7.z, acc.z); acc.w = fmaf(w7, e7.w, acc.w);
    }

    ushort4 o;
    o.x = f2bf(acc.x); o.y = f2bf(acc.y);
    o.z = f2bf(acc.z); o.w = f2bf(acc.w);
    *(ushort4*)&aggb[(size_t)row * DIM + lane * 4] = o;
}

// ---------------------------------------------------------------------------
// Tiny kernel: WpT[n][k] = bf16(Wp[k][n]).  (unchanged)
// ---------------------------------------------------------------------------
__global__ __launch_bounds__(256) void wp_convert_kernel(
    const float* __restrict__ Wp, ushort* __restrict__ WpT)
{
    const int k = blockIdx.x;
    const int n = threadIdx.x;
    WpT[(size_t)n * DIM + k] = f2bf(Wp[(size_t)k * DIM + n]);
}

// ---------------------------------------------------------------------------
// Kernel B: out = agg @ Wp + bp via bf16 MFMA (fp32 accumulate). (unchanged)
// ---------------------------------------------------------------------------
__global__ __launch_bounds__(256) void mfma_gemm_kernel(
    const ushort* __restrict__ A,     // [M, 256] bf16
    const ushort* __restrict__ BT,    // [256, 256] bf16 (transposed Wp)
    const float*  __restrict__ bp,    // [256]
    float* __restrict__ out)          // [M, 256]
{
    __shared__ ushort ldsA[64 * 40];
    __shared__ ushort ldsB[64 * 40];

    const int tid  = threadIdx.x;
    const int mb   = blockIdx.x * 64;
    const int nb   = blockIdx.y * 64;
    const int wave = tid >> 6;
    const int lane = tid & 63;
    const int r0   = (wave >> 1) * 32;
    const int c0   = (wave & 1) * 32;
    const int lrow = lane & 15;
    const int kgrp = lane >> 4;

    const int sm = tid >> 2;
    const int sc = (tid & 3) * 8;

    f32x4 acc00 = {0.f, 0.f, 0.f, 0.f};
    f32x4 acc01 = {0.f, 0.f, 0.f, 0.f};
    f32x4 acc10 = {0.f, 0.f, 0.f, 0.f};
    f32x4 acc11 = {0.f, 0.f, 0.f, 0.f};

    for (int kb = 0; kb < DIM; kb += 32) {
        *(uint4*)&ldsA[sm * 40 + sc] =
            *(const uint4*)&A[(size_t)(mb + sm) * DIM + kb + sc];
        *(uint4*)&ldsB[sm * 40 + sc] =
            *(const uint4*)&BT[(size_t)(nb + sm) * DIM + kb + sc];
        __syncthreads();

        const short8 a0 = *(const short8*)&ldsA[(r0 + lrow)      * 40 + kgrp * 8];
        const short8 a1 = *(const short8*)&ldsA[(r0 + 16 + lrow) * 40 + kgrp * 8];
        const short8 b0 = *(const short8*)&ldsB[(c0 + lrow)      * 40 + kgrp * 8];
        const short8 b1 = *(const short8*)&ldsB[(c0 + 16 + lrow) * 40 + kgrp * 8];

        acc00 = __builtin_amdgcn_mfma_f32_16x16x32_bf16(a0, b0, acc00, 0, 0, 0);
        acc01 = __builtin_amdgcn_mfma_f32_16x16x32_bf16(a0, b1, acc01, 0, 0, 0);
        acc10 = __builtin_amdgcn_mfma_f32_16x16x32_bf16(a1, b0, acc10, 0, 0, 0);
        acc11 = __builtin_amdgcn_mfma_f32_16x16x32_bf16(a1, b1, acc11, 0, 0, 0);
        __syncthreads();
    }

    const int orow = mb + r0 + kgrp * 4;
    const int ocol = nb + c0 + lrow;
    const float bp0 = bp[ocol];
    const float bp1 = bp[ocol + 16];
    #pragma unroll
    for (int reg = 0; reg < 4; ++reg) {
        out[(size_t)(orow + reg)      * DIM + ocol]      = acc00[reg] + bp0;
        out[(size_t)(orow + reg)      * DIM + ocol + 16] = acc01[reg] + bp1;
        out[(size_t)(orow + 16 + reg) * DIM + ocol]      = acc10[reg] + bp0;
        out[(size_t)(orow + 16 + reg) * DIM + ocol + 16] = acc11[reg] + bp1;
    }
}

// ---------------------------------------------------------------------------
extern "C" void kernel_launch(void* const* d_in, const int* in_sizes, int n_in,
                              void* d_out, int out_size, void* d_ws, size_t ws_size,
                              hipStream_t stream)
{
    const float* SADQ = (const float*)d_in[0];
    const float* E    = (const float*)d_in[1];
    const float* Wo   = (const float*)d_in[2];
    const float* bo   = (const float*)d_in[3];
    const float* Wa   = (const float*)d_in[4];
    const float* ba   = (const float*)d_in[5];
    const float* Wr   = (const float*)d_in[6];
    const float* br   = (const float*)d_in[7];
    const float* Wp   = (const float*)d_in[8];
    const float* bp   = (const float*)d_in[9];
    const int*   Hp   = (const int*)d_in[10];
    const int*   Wdp  = (const int*)d_in[11];

    const int BM = in_sizes[0] / DIM;          // 8192 rows

    // Workspace layout (bytes, all 256B-aligned):
    //   aggb: [BM][256] bf16      @ 0          4,194,304
    //   WpT : [256][256] bf16     @ 4,194,304    131,072
    //   P   : [BM][112] fp32      @ 4,325,376  3,670,016
    //   WcTh: [128][256] bf16     @ 7,995,392     65,536
    //   WcTl: [128][256] bf16     @ 8,060,928     65,536
    //   bcat: [128] fp32          @ 8,126,464        512
    //   Ahi : [BM][256] bf16      @ 8,126,976  4,194,304
    //   Alo : [BM][256] bf16      @12,321,280  4,194,304
    //   total ~16.5 MB
    char* ws = (char*)d_ws;
    ushort* aggb = (ushort*)(ws);
    ushort* WpT  = (ushort*)(ws + 4194304);
    float*  P    = (float*) (ws + 4325376);
    ushort* WcTh = (ushort*)(ws + 7995392);
    ushort* WcTl = (ushort*)(ws + 8060928);
    float*  bcat = (float*) (ws + 8126464);
    ushort* Ahi  = (ushort*)(ws + 8126976);
    ushort* Alo  = (ushort*)(ws + 12321280);
    float*  out  = (float*)d_out;

    sadq_split_kernel<<<(BM * DIM / 4) / 256, 256, 0, stream>>>(SADQ, Ahi, Alo);
    wsplit_build_kernel<<<DIM, NPAD, 0, stream>>>(Wo, bo, Wa, ba, Wr, br,
                                                  WcTh, WcTl, bcat);
    dim3 gp(BM / 64, NPAD / 64);
    proj_mfma_kernel<<<gp, 256, 0, stream>>>(Ahi, Alo, WcTh, WcTl, bcat, P);

    gather_kernel<<<BM / 4, 256, 0, stream>>>(P, E, Hp, Wdp, aggb);
    wp_convert_kernel<<<DIM, 256, 0, stream>>>(Wp, WpT);

    dim3 g2(BM / 64, DIM / 64);
    mfma_gemm_kernel<<<g2, 256, 0, stream>>>(aggb, WpT, bp, out);
}